// Round 15
// baseline (54.198 us; speedup 1.0000x reference)
//
#include <hip/hip_runtime.h>
#include <stdint.h>

#define LL   2000
#define NB   512
#define CIN  32
#define COUT 32
#define SPOS 128        // positions per wave-strip (64 lanes x 2)
#define NST  16         // strips per n (last has 80 valid positions)
// grid = NB * NST / 4 = 2048 blocks of 256 (4 autonomous waves each)

typedef float f32x2 __attribute__((ext_vector_type(2)));

#define TAP(nzx, snx, wz, ws) \
    { uint32_t t1 = (nzx) & (wz); uint32_t t2 = ((snx) ^ (ws)) & t1; \
      P += __popc(t1); Q += __popc(t2); }

// declare burst registers
#define DECL(i) f32x2 vv##i;
// issue one dwordx2 load for ci=i (asm: stays in flight, compiler can't sink)
#define LDI(i) { const uint32_t off = base + (uint32_t)(i * LL * 4); \
    asm volatile("global_load_dwordx2 %0, %1, %2" : "=v"(vv##i) : "v"(off), "s"(xn)); }
// pack ci=i into the 2 position masks
#define PKI(i) { const uint32_t ux = __float_as_uint(vv##i.x); \
    const uint32_t uy = __float_as_uint(vv##i.y); \
    const uint32_t nx = (ux << 1) ? 1u : 0u; \
    const uint32_t ny = (uy << 1) ? 1u : 0u; \
    nz0 |= nx << i;  sn0 |= ((ux >> 31) & nx) << i; \
    nz1 |= ny << i;  sn1 |= ((uy >> 31) & ny) << i; }
// tie 8 burst registers to a vmcnt(0) (ext_vector "+v" ties are supported; r9)
#define W8(a,b,c,d,e,f,g2,h2) \
    asm volatile("s_waitcnt vmcnt(0)" : "+v"(vv##a), "+v"(vv##b), "+v"(vv##c), \
        "+v"(vv##d), "+v"(vv##e), "+v"(vv##f), "+v"(vv##g2), "+v"(vv##h2) :: "memory");

// ---------------- single fused kernel: wave-autonomous strips -----------------
__global__ __launch_bounds__(256, 4) void fused_kernel(const float* __restrict__ x,
                                                       const float* __restrict__ w,
                                                       const float* __restrict__ osc,
                                                       const float* __restrict__ lsc,
                                                       float* __restrict__ out) {
    __shared__ uint32_t wlds[256];   // wlds[co*8 + k*2 + {nz,sn}]
    __shared__ float    olds[COUT];

    const int b   = blockIdx.x;
    const int n   = b >> 2;
    const int seg = b & 3;
    const int t   = threadIdx.x;
    const int wid = t >> 6;
    const int q   = t & 63;
    const int S   = (seg * 4 + wid) * SPOS;   // strip base position
    const float* xn = x + (size_t)n * (CIN * LL);
    float* on = out + (size_t)n * (COUT * LL);

    // ---- stage weight masks + o_scale in LDS (once; only barrier in kernel)
    if (t < COUT) olds[t] = osc[t];
    if (t < COUT * 3) {
        const int co = t / 3, k = t % 3;
        uint32_t nz = 0, sn = 0;
        #pragma unroll
        for (int ci = 0; ci < CIN; ++ci) {
            const float vw = w[(co * CIN + ci) * 3 + k];
            nz |= ((uint32_t)(vw != 0.0f)) << ci;
            sn |= ((uint32_t)(vw <  0.0f)) << ci;
        }
        wlds[co * 8 + k * 2]     = nz;
        wlds[co * 8 + k * 2 + 1] = sn;
    }

    // ---- this lane's 2 positions; lsc preloaded (compiler-tracked, pre-burst)
    const int  l     = S + 2 * q;
    const bool valid = (l < LL);              // LL even -> l and l+1 together
    const int  la    = valid ? l : (LL - 2);
    f32x2 lsv = *(const f32x2*)(lsc + la);
    asm volatile("" :: "v"(lsv.x), "v"(lsv.y));

    __syncthreads();

    // ---- 33-deep asm load burst: 32 ci rows (dwordx2) + 1 halo dword
    DECL(0)  DECL(1)  DECL(2)  DECL(3)  DECL(4)  DECL(5)  DECL(6)  DECL(7)
    DECL(8)  DECL(9)  DECL(10) DECL(11) DECL(12) DECL(13) DECL(14) DECL(15)
    DECL(16) DECL(17) DECL(18) DECL(19) DECL(20) DECL(21) DECL(22) DECL(23)
    DECL(24) DECL(25) DECL(26) DECL(27) DECL(28) DECL(29) DECL(30) DECL(31)
    const uint32_t base = (uint32_t)(la * 4);
    LDI(0)  LDI(1)  LDI(2)  LDI(3)  LDI(4)  LDI(5)  LDI(6)  LDI(7)
    LDI(8)  LDI(9)  LDI(10) LDI(11) LDI(12) LDI(13) LDI(14) LDI(15)
    LDI(16) LDI(17) LDI(18) LDI(19) LDI(20) LDI(21) LDI(22) LDI(23)
    LDI(24) LDI(25) LDI(26) LDI(27) LDI(28) LDI(29) LDI(30) LDI(31)

    // halo: lanes 0..31 -> column S-1 (ci=q), lanes 32..63 -> column S+SPOS (ci=q-32)
    const int  hc = (q < 32) ? (S - 1) : (S + SPOS);
    const bool hv = (hc >= 0) && (hc < LL);
    uint32_t hu;
    {
        const uint32_t hoff = (uint32_t)((((q & 31) * LL) + (hv ? hc : 0)) * 4);
        asm volatile("global_load_dword %0, %1, %2" : "=v"(hu) : "v"(hoff), "s"(xn));
    }

    // ---- drain the burst (ties keep consumers behind the wait)
    W8(0,1,2,3,4,5,6,7)  W8(8,9,10,11,12,13,14,15)
    W8(16,17,18,19,20,21,22,23)  W8(24,25,26,27,28,29,30,31)
    asm volatile("s_waitcnt vmcnt(0)" : "+v"(hu) :: "memory");
    __builtin_amdgcn_sched_barrier(0);

    // ---- pack 2 position masks across 32 ci
    uint32_t nz0 = 0, sn0 = 0, nz1 = 0, sn1 = 0;
    PKI(0)  PKI(1)  PKI(2)  PKI(3)  PKI(4)  PKI(5)  PKI(6)  PKI(7)
    PKI(8)  PKI(9)  PKI(10) PKI(11) PKI(12) PKI(13) PKI(14) PKI(15)
    PKI(16) PKI(17) PKI(18) PKI(19) PKI(20) PKI(21) PKI(22) PKI(23)
    PKI(24) PKI(25) PKI(26) PKI(27) PKI(28) PKI(29) PKI(30) PKI(31)
    if (!valid) { nz0 = 0; sn0 = 0; nz1 = 0; sn1 = 0; }

    // ---- halo ballots (all lanes active)
    const bool hnz = hv && ((hu << 1) != 0);
    const bool hng = hnz && ((hu >> 31) != 0);
    const unsigned long long bnz = __ballot(hnz);
    const unsigned long long bng = __ballot(hng);

    // ---- neighbor masks via shuffle
    uint32_t xmn = __shfl_up(nz1, 1u);    // pack(l-1) from lane-1
    uint32_t xms = __shfl_up(sn1, 1u);
    uint32_t xqn = __shfl_down(nz0, 1u);  // pack(l+2) from lane+1
    uint32_t xqs = __shfl_down(sn0, 1u);
    if (q == 0)  { xmn = (uint32_t)bnz;         xms = (uint32_t)bng;         }
    if (q == 63) { xqn = (uint32_t)(bnz >> 32); xqs = (uint32_t)(bng >> 32); }

    if (!valid) return;

    // ---- conv: 2 positions x 32 co, NT stores
    float* o = on + l;
    #pragma unroll 8
    for (int co = 0; co < COUT; ++co) {
        const uint32_t wz0 = wlds[co*8+0], ws0 = wlds[co*8+1];
        const uint32_t wz1 = wlds[co*8+2], ws1 = wlds[co*8+3];
        const uint32_t wz2 = wlds[co*8+4], ws2 = wlds[co*8+5];
        const float os = olds[co];

        int P = 0, Q = 0;
        TAP(xmn, xms, wz0, ws0) TAP(nz0, sn0, wz1, ws1) TAP(nz1, sn1, wz2, ws2)
        const int d0 = P - 2 * Q;
        P = 0; Q = 0;
        TAP(nz0, sn0, wz0, ws0) TAP(nz1, sn1, wz1, ws1) TAP(xqn, xqs, wz2, ws2)
        const int d1 = P - 2 * Q;

        f32x2 r;
        r.x = (float)d0 * os * lsv.x;
        r.y = (float)d1 * os * lsv.y;
        __builtin_nontemporal_store(r, (f32x2*)(o + (size_t)co * LL));
    }
}

extern "C" void kernel_launch(void* const* d_in, const int* in_sizes, int n_in,
                              void* d_out, int out_size, void* d_ws, size_t ws_size,
                              hipStream_t stream) {
    const float* x   = (const float*)d_in[0];
    const float* w   = (const float*)d_in[1];
    const float* osc = (const float*)d_in[2];
    const float* lsc = (const float*)d_in[3];
    float* out = (float*)d_out;

    fused_kernel<<<NB * NST / 4, 256, 0, stream>>>(x, w, osc, lsc, out);
}